// Round 7
// baseline (295.423 us; speedup 1.0000x reference)
//
#include <hip/hip_runtime.h>
#include <hip/hip_bf16.h>
#include <math.h>

typedef __bf16 bf16_t;
typedef __bf16 bf16x8 __attribute__((ext_vector_type(8)));
typedef __bf16 bf16x2 __attribute__((ext_vector_type(2)));
typedef unsigned short ushort8v __attribute__((ext_vector_type(8)));
typedef float floatx4 __attribute__((ext_vector_type(4)));

static __device__ inline unsigned short f2bf_rne(float f) {
    unsigned int u = __builtin_bit_cast(unsigned int, f);
    unsigned int r = u + 0x7FFFu + ((u >> 16) & 1u);
    return (unsigned short)(r >> 16);
}
static __device__ inline bf16_t f2bf(float f) {
    return __builtin_bit_cast(bf16_t, f2bf_rne(f));
}

// packed f32x2 -> bf16x2 (hw v_cvt_pk_bf16_f32 on gfx950)
#if __has_builtin(__builtin_amdgcn_cvt_pk_bf16_f32)
static __device__ inline unsigned pk2bf(float a, float b) {
    bf16x2 v = __builtin_amdgcn_cvt_pk_bf16_f32(a, b);
    return __builtin_bit_cast(unsigned, v);
}
#else
static __device__ inline unsigned pk2bf(float a, float b) {
    return (unsigned)f2bf_rne(a) | ((unsigned)f2bf_rne(b) << 16);
}
#endif

#if __has_builtin(__builtin_amdgcn_exp2f)
#define EXP2F __builtin_amdgcn_exp2f
#else
#define EXP2F exp2f
#endif

static __device__ inline bf16x8 load8(const bf16_t* p) { return *(const bf16x8*)p; }
static __device__ inline bf16x8 load8(const float* p) {
    float4 a = *(const float4*)p;
    float4 b = *(const float4*)(p + 4);
    ushort8v u;
    u[0] = f2bf_rne(a.x); u[1] = f2bf_rne(a.y); u[2] = f2bf_rne(a.z); u[3] = f2bf_rne(a.w);
    u[4] = f2bf_rne(b.x); u[5] = f2bf_rne(b.y); u[6] = f2bf_rne(b.z); u[7] = f2bf_rne(b.w);
    return __builtin_bit_cast(bf16x8, u);
}
static __device__ inline bf16x8 load8sum4(const float* p, size_t s) {
    float4 a0 = *(const float4*)p,           a1 = *(const float4*)(p + 4);
    float4 b0 = *(const float4*)(p + s),     b1 = *(const float4*)(p + s + 4);
    float4 c0 = *(const float4*)(p + 2 * s), c1 = *(const float4*)(p + 2 * s + 4);
    float4 d0 = *(const float4*)(p + 3 * s), d1 = *(const float4*)(p + 3 * s + 4);
    ushort8v u;
    u[0] = f2bf_rne((a0.x + b0.x) + (c0.x + d0.x));
    u[1] = f2bf_rne((a0.y + b0.y) + (c0.y + d0.y));
    u[2] = f2bf_rne((a0.z + b0.z) + (c0.z + d0.z));
    u[3] = f2bf_rne((a0.w + b0.w) + (c0.w + d0.w));
    u[4] = f2bf_rne((a1.x + b1.x) + (c1.x + d1.x));
    u[5] = f2bf_rne((a1.y + b1.y) + (c1.y + d1.y));
    u[6] = f2bf_rne((a1.z + b1.z) + (c1.z + d1.z));
    u[7] = f2bf_rne((a1.w + b1.w) + (c1.w + d1.w));
    return __builtin_bit_cast(bf16x8, u);
}

static __device__ inline void store_c(float* C, size_t i, float v) { C[i] = v; }
static __device__ inline void store_c(bf16_t* C, size_t i, float v) { C[i] = f2bf(v); }

// ---------------------------------------------------------------------------
// GEMM body: C[M,N] = A[M,K]*B[N,K]^T (+bias_col[n])(+bias_row[m]).
// TM=128, TN=64, BK=32; LDS stride 68 (zero-conflict).
// ---------------------------------------------------------------------------
template <int AMODE, typename TA, typename TB, typename TC>
__device__ inline void gemm_body(
    const TA* __restrict__ A, size_t astride, int lda,
    const TB* __restrict__ B, int ldb,
    const float* __restrict__ bias_col, const float* __restrict__ bias_row,
    TC* __restrict__ C, int ldc, int K, int m0, int n0)
{
    __shared__ bf16_t As[128 * 68];
    __shared__ bf16_t Bs[64 * 68];

    const int tid = threadIdx.x;
    const int lane = tid & 63, wave = tid >> 6;
    const int wm = wave & 1, wn = wave >> 1;
    const int lo16 = lane & 15, quad = lane >> 4;
    const int sr = tid >> 2, sc = (tid & 3) * 8;

    floatx4 acc[4][2] = {};

    for (int k0 = 0; k0 < K; k0 += 32) {
        bf16x8 a0, a1, b0;
        const size_t ia0 = (size_t)(m0 + sr) * lda + k0 + sc;
        const size_t ia1 = (size_t)(m0 + 64 + sr) * lda + k0 + sc;
        if (AMODE == 1) {
            a0 = load8sum4((const float*)A + ia0, astride);
            a1 = load8sum4((const float*)A + ia1, astride);
        } else {
            a0 = load8(A + ia0);
            a1 = load8(A + ia1);
        }
        b0 = load8(B + (size_t)(n0 + sr) * ldb + k0 + sc);
        __syncthreads();
        *(bf16x8*)(&As[sr * 68 + sc]) = a0;
        *(bf16x8*)(&As[(64 + sr) * 68 + sc]) = a1;
        *(bf16x8*)(&Bs[sr * 68 + sc]) = b0;
        __syncthreads();

        bf16x8 af[4], bfv[2];
#pragma unroll
        for (int mt = 0; mt < 4; ++mt)
            af[mt] = *(const bf16x8*)(&As[(wm * 64 + mt * 16 + lo16) * 68 + quad * 8]);
#pragma unroll
        for (int nt = 0; nt < 2; ++nt)
            bfv[nt] = *(const bf16x8*)(&Bs[(wn * 32 + nt * 16 + lo16) * 68 + quad * 8]);
#pragma unroll
        for (int mt = 0; mt < 4; ++mt)
#pragma unroll
            for (int nt = 0; nt < 2; ++nt)
                acc[mt][nt] = __builtin_amdgcn_mfma_f32_16x16x32_bf16(
                    af[mt], bfv[nt], acc[mt][nt], 0, 0, 0);
    }

#pragma unroll
    for (int nt = 0; nt < 2; ++nt) {
        const int gn = n0 + wn * 32 + nt * 16 + lo16;
        const float bc = bias_col ? bias_col[gn] : 0.f;
#pragma unroll
        for (int mt = 0; mt < 4; ++mt) {
#pragma unroll
            for (int r = 0; r < 4; ++r) {
                const int gm = m0 + wm * 64 + mt * 16 + quad * 4 + r;
                float v = acc[mt][nt][r] + bc;
                if (bias_row) v += bias_row[gm];
                store_c(C, (size_t)gm * ldc + gn, v);
            }
        }
    }
}

// Fused: 0-255 q-proj, 256-511 k-proj, 512-767 vt-proj, 768-1023 sg convert.
__global__ __launch_bounds__(256) void proj_qkv(
    const float* __restrict__ query, const float* __restrict__ Wq, const float* __restrict__ bq,
    const float* __restrict__ key,   const float* __restrict__ Wk, const float* __restrict__ bk,
    const float* __restrict__ Wv,    const float* __restrict__ value, const float* __restrict__ bv,
    const float* __restrict__ sg,    bf16_t* __restrict__ sgb,
    bf16_t* __restrict__ q, bf16_t* __restrict__ k, bf16_t* __restrict__ vt)
{
    const int b = blockIdx.x;
    if (b >= 768) {
        const size_t base = (size_t)(b - 768) * 65536 + threadIdx.x * 8;
#pragma unroll 4
        for (int it = 0; it < 32; ++it) {
            const size_t idx = base + (size_t)it * 2048;
            float4 a = *(const float4*)(sg + idx);
            float4 c = *(const float4*)(sg + idx + 4);
            ushort8v u;
            u[0] = f2bf_rne(a.x); u[1] = f2bf_rne(a.y); u[2] = f2bf_rne(a.z); u[3] = f2bf_rne(a.w);
            u[4] = f2bf_rne(c.x); u[5] = f2bf_rne(c.y); u[6] = f2bf_rne(c.z); u[7] = f2bf_rne(c.w);
            *(ushort8v*)(sgb + idx) = u;
        }
        return;
    }
    const float *A, *B, *bc = nullptr, *br = nullptr;
    bf16_t* C;
    int ldc = 512, m0, n0;
    if (b < 512) {
        int i = b & 255, x = i & 7, t = i >> 3;
        n0 = (t & 7) * 64;
        m0 = ((t >> 3) * 8 + x) * 128;
        if (b < 256) { A = query; B = Wq; bc = bq; C = q; }
        else         { A = key;   B = Wk; bc = bk; C = k; }
    } else {
        int i = b - 512;
        n0 = (i & 63) * 64;
        m0 = (i >> 6) * 128;
        A = Wv; B = value; br = bv; C = vt; ldc = 4096;
    }
    gemm_body<0, float, float, bf16_t>(A, 0, 512, B, 512, bc, br, C, ldc, 512, m0, n0);
}

// sgconv: bf16 x bf16, TM=TN=128, BK=32, 4-way K-split (grid 512).
__global__ __launch_bounds__(256) void sgconv_gemm(
    const bf16_t* __restrict__ sgb, const bf16_t* __restrict__ aot,
    float* __restrict__ part)
{
    const int i = blockIdx.x & 127;
    const int kb = blockIdx.x >> 7;
    const int ms = i & 31, ns = i >> 5;
    const int m0 = ms * 128, n0 = ns * 128;
    const int kbase = kb * 1024;

    __shared__ bf16_t As[128 * 68];
    __shared__ bf16_t Bs[128 * 68];

    const int tid = threadIdx.x;
    const int lane = tid & 63, wave = tid >> 6;
    const int wm = wave & 1, wn = wave >> 1;
    const int lo16 = lane & 15, quad = lane >> 4;
    const int sr = tid >> 1, sc = (tid & 1) * 16;

    const bf16_t* asrc = sgb + (size_t)(m0 + sr) * 4096 + kbase + sc;
    const bf16_t* bsrc = aot + (size_t)(n0 + sr) * 4096 + kbase + sc;

    floatx4 acc[4][4] = {};

    for (int k0 = 0; k0 < 1024; k0 += 32) {
        bf16x8 a0 = *(const bf16x8*)(asrc + k0);
        bf16x8 a1 = *(const bf16x8*)(asrc + k0 + 8);
        bf16x8 b0 = *(const bf16x8*)(bsrc + k0);
        bf16x8 b1 = *(const bf16x8*)(bsrc + k0 + 8);
        __syncthreads();
        *(bf16x8*)(&As[sr * 68 + sc]) = a0;
        *(bf16x8*)(&As[sr * 68 + sc + 8]) = a1;
        *(bf16x8*)(&Bs[sr * 68 + sc]) = b0;
        *(bf16x8*)(&Bs[sr * 68 + sc + 8]) = b1;
        __syncthreads();

        bf16x8 af[4], bfv[4];
#pragma unroll
        for (int mt = 0; mt < 4; ++mt)
            af[mt] = *(const bf16x8*)(&As[(wm * 64 + mt * 16 + lo16) * 68 + quad * 8]);
#pragma unroll
        for (int nt = 0; nt < 4; ++nt)
            bfv[nt] = *(const bf16x8*)(&Bs[(wn * 64 + nt * 16 + lo16) * 68 + quad * 8]);
#pragma unroll
        for (int mt = 0; mt < 4; ++mt)
#pragma unroll
            for (int nt = 0; nt < 4; ++nt)
                acc[mt][nt] = __builtin_amdgcn_mfma_f32_16x16x32_bf16(
                    af[mt], bfv[nt], acc[mt][nt], 0, 0, 0);
    }

    float* pw = part + (size_t)kb * (4096 * 512);
#pragma unroll
    for (int mt = 0; mt < 4; ++mt)
#pragma unroll
        for (int r = 0; r < 4; ++r) {
            const int gm = m0 + wm * 64 + mt * 16 + quad * 4 + r;
#pragma unroll
            for (int nt = 0; nt < 4; ++nt)
                pw[(size_t)gm * 512 + n0 + wn * 64 + nt * 16 + lo16] = acc[mt][nt][r];
        }
}

// out = (sum of 4 partials) @ Wo^T + bo
__global__ __launch_bounds__(256) void out_proj(
    const float* __restrict__ p, const float* __restrict__ Wo,
    const float* __restrict__ bo, float* __restrict__ out)
{
    const int i = blockIdx.x, x = i & 7, t = i >> 3;
    const int n0 = (t & 7) * 64, m0 = ((t >> 3) * 8 + x) * 128;
    gemm_body<1, float, float, float>(p, (size_t)4096 * 512, 512, Wo, 512,
                                      bo, nullptr, out, 512, 512, m0, n0);
}

// ---------------------------------------------------------------------------
// Flash attention v4: stride-68 LDS everywhere (measured-0-conflict pattern),
// hw packed bf16 cvt, exp2 with folded scale, ones-row MFMA for the softmax
// denominator (replaces 32 VALU adds/iter + epilogue shuffles).
// ---------------------------------------------------------------------------
__global__ __launch_bounds__(256, 4) void flash_attn(
    const bf16_t* __restrict__ q, const bf16_t* __restrict__ kk,
    const bf16_t* __restrict__ vt, float* __restrict__ op,
    float* __restrict__ lp, float scale2 /* scale*log2(e) */)
{
    const int N = 4096, D = 512;
    const int h   = blockIdx.x & 7;
    const int qb  = (blockIdx.x >> 3) & 31;
    const int qtr = blockIdx.x >> 8;
    const int t0  = qtr * 1024;

    const int tid = threadIdx.x;
    const int w = tid >> 6, lane = tid & 63;
    const int lo16 = lane & 15, quad = lane >> 4;

    __shared__ bf16_t Ks[64 * 68];      // [tok][dim]
    __shared__ bf16_t Vs[64 * 68];      // [dim][tok]
    __shared__ bf16_t Ps[4][32 * 68];   // per-wave P [q][tok]

    const bf16_t* qp = q + (size_t)(qb * 128 + w * 32 + lo16) * D + h * 64 + quad * 8;
    bf16x8 qf[2][2];
    qf[0][0] = *(const bf16x8*)qp;
    qf[0][1] = *(const bf16x8*)(qp + 32);
    qf[1][0] = *(const bf16x8*)(qp + 16 * D);
    qf[1][1] = *(const bf16x8*)(qp + 16 * D + 32);

    // ones fragment for the denominator MFMA
    ushort8v onesu;
#pragma unroll
    for (int i = 0; i < 8; ++i) onesu[i] = 0x3F80;  // bf16 1.0
    const bf16x8 ones = __builtin_bit_cast(bf16x8, onesu);

    const int srow = tid >> 2, sc = (tid & 3) * 16;
    const bf16_t* ksrc = kk + (size_t)(t0 + srow) * D + h * 64 + sc;
    const bf16_t* vsrc = vt + (size_t)(h * 64 + srow) * N + t0 + sc;
    bf16_t* kdst = &Ks[srow * 68 + sc];
    bf16_t* vdst = &Vs[srow * 68 + sc];

    floatx4 o[4][2] = {};
    floatx4 ol[2] = {};   // denominator accumulator (all rows equal)

    bf16x8 kr0 = *(const bf16x8*)ksrc;
    bf16x8 kr1 = *(const bf16x8*)(ksrc + 8);
    bf16x8 vr0 = *(const bf16x8*)vsrc;
    bf16x8 vr1 = *(const bf16x8*)(vsrc + 8);

    for (int it = 0; it < 16; ++it) {
        __syncthreads();
        *(bf16x8*)kdst = kr0;  *(bf16x8*)(kdst + 8) = kr1;
        *(bf16x8*)vdst = vr0;  *(bf16x8*)(vdst + 8) = vr1;
        __syncthreads();
        if (it < 15) {
            const bf16_t* kn = ksrc + (size_t)(it + 1) * 64 * D;
            const bf16_t* vn = vsrc + (it + 1) * 64;
            kr0 = *(const bf16x8*)kn;  kr1 = *(const bf16x8*)(kn + 8);
            vr0 = *(const bf16x8*)vn;  vr1 = *(const bf16x8*)(vn + 8);
        }

        // S^T = K·Q^T : D[m=tok][n=q]
        floatx4 s[4][2];
#pragma unroll
        for (int tt = 0; tt < 4; ++tt) {
            bf16x8 kf0 = *(const bf16x8*)(&Ks[(tt * 16 + lo16) * 68 + quad * 8]);
            bf16x8 kf1 = *(const bf16x8*)(&Ks[(tt * 16 + lo16) * 68 + 32 + quad * 8]);
#pragma unroll
            for (int qt = 0; qt < 2; ++qt) {
                floatx4 a = {};
                a = __builtin_amdgcn_mfma_f32_16x16x32_bf16(kf0, qf[qt][0], a, 0, 0, 0);
                a = __builtin_amdgcn_mfma_f32_16x16x32_bf16(kf1, qf[qt][1], a, 0, 0, 0);
                s[tt][qt] = a;
            }
        }
        // exp2(x*scale2) + packed cvt + b64 P writes (stride 68, conflict-free)
#pragma unroll
        for (int tt = 0; tt < 4; ++tt)
#pragma unroll
            for (int qt = 0; qt < 2; ++qt) {
                float e0 = EXP2F(s[tt][qt][0] * scale2);
                float e1 = EXP2F(s[tt][qt][1] * scale2);
                float e2 = EXP2F(s[tt][qt][2] * scale2);
                float e3 = EXP2F(s[tt][qt][3] * scale2);
                uint2 pk;
                pk.x = pk2bf(e0, e1);
                pk.y = pk2bf(e2, e3);
                *(uint2*)(&Ps[w][(qt * 16 + lo16) * 68 + tt * 16 + quad * 4]) = pk;
            }
        // PV + denominator: o[dim][q] += V·P^T ; ol[q] += 1·P^T
#pragma unroll
        for (int ks = 0; ks < 2; ++ks) {
            bf16x8 pf0 = *(const bf16x8*)(&Ps[w][lo16 * 68 + ks * 32 + quad * 8]);
            bf16x8 pf1 = *(const bf16x8*)(&Ps[w][(16 + lo16) * 68 + ks * 32 + quad * 8]);
            ol[0] = __builtin_amdgcn_mfma_f32_16x16x32_bf16(ones, pf0, ol[0], 0, 0, 0);
            ol[1] = __builtin_amdgcn_mfma_f32_16x16x32_bf16(ones, pf1, ol[1], 0, 0, 0);
#pragma unroll
            for (int t = 0; t < 4; ++t) {
                bf16x8 vf = *(const bf16x8*)(&Vs[(t * 16 + lo16) * 68 + ks * 32 + quad * 8]);
                o[t][0] = __builtin_amdgcn_mfma_f32_16x16x32_bf16(vf, pf0, o[t][0], 0, 0, 0);
                o[t][1] = __builtin_amdgcn_mfma_f32_16x16x32_bf16(vf, pf1, o[t][1], 0, 0, 0);
            }
        }
    }

    const int g = blockIdx.x & 255;
    float* opw = op + ((size_t)qtr * 256 + g) * 8192;
#pragma unroll
    for (int t = 0; t < 4; ++t)
#pragma unroll
        for (int pt = 0; pt < 2; ++pt)
#pragma unroll
            for (int r = 0; r < 4; ++r)
                opw[(t * 16 + quad * 4 + r) * 128 + w * 32 + pt * 16 + lo16] = o[t][pt][r];

    if (quad == 0) {   // ol rows all equal; col = q
        float* lpw = lp + ((size_t)qtr * 256 + g) * 128;
        lpw[w * 32 + lo16] = ol[0][0];
        lpw[w * 32 + 16 + lo16] = ol[1][0];
    }
}

__global__ __launch_bounds__(256) void attn_combine(
    const float* __restrict__ op, const float* __restrict__ lp, bf16_t* __restrict__ aot)
{
    const int g = blockIdx.x;
    const int h = g & 7, qb = g >> 3;
    const int tid = threadIdx.x;
    __shared__ float ls[128];
    if (tid < 128) {
        float s = 0.f;
#pragma unroll
        for (int qtr = 0; qtr < 4; ++qtr)
            s += lp[((size_t)qtr * 256 + g) * 128 + tid];
        ls[tid] = 1.0f / s;
    }
    __syncthreads();
    const float* b0 = op + (size_t)g * 8192;
    const size_t QS = (size_t)256 * 8192;
#pragma unroll 4
    for (int i = 0; i < 32; ++i) {
        int idx = i * 256 + tid;
        float v = b0[idx] + b0[QS + idx] + b0[2 * QS + idx] + b0[3 * QS + idx];
        int dim = idx >> 7, qc = idx & 127;
        aot[(size_t)(h * 64 + dim) * 4096 + qb * 128 + qc] = f2bf(v * ls[qc]);
    }
}

extern "C" void kernel_launch(void* const* d_in, const int* in_sizes, int n_in,
                              void* d_out, int out_size, void* d_ws, size_t ws_size,
                              hipStream_t stream)
{
    const int N = 4096, D = 512;
    const float* query = (const float*)d_in[0];
    const float* key_t = (const float*)d_in[1];
    const float* value = (const float*)d_in[2];
    const float* Wq = (const float*)d_in[3];
    const float* bq = (const float*)d_in[4];
    const float* Wk = (const float*)d_in[5];
    const float* bk = (const float*)d_in[6];
    const float* Wv = (const float*)d_in[7];
    const float* bv = (const float*)d_in[8];
    const float* Wo = (const float*)d_in[9];
    const float* bo = (const float*)d_in[10];
    const float* sg = (const float*)d_in[11];
    float* out = (float*)d_out;

    bf16_t* q   = (bf16_t*)d_ws;
    bf16_t* kk  = q   + (size_t)N * D;
    bf16_t* vt  = kk  + (size_t)N * D;
    bf16_t* aot = vt  + (size_t)N * D;
    float*  op  = (float*)(aot + (size_t)N * D);
    float*  lp  = op + (size_t)4 * 256 * 8192;
    bf16_t* sgb = (bf16_t*)(lp + (size_t)4 * 256 * 128);
    float*  p   = op;   // sgconv partials alias op (dead after combine)

    const dim3 blk(256);

    proj_qkv<<<1024, blk, 0, stream>>>(query, Wq, bq, key_t, Wk, bk,
                                       Wv, value, bv, sg, sgb, q, kk, vt);

    const float scale2 = 1.4426950408889634f / sqrtf((float)D);
    flash_attn<<<1024, blk, 0, stream>>>(q, kk, vt, op, lp, scale2);
    attn_combine<<<256, blk, 0, stream>>>(op, lp, aot);

    sgconv_gemm<<<512, blk, 0, stream>>>(sgb, aot, p);
    out_proj<<<256, blk, 0, stream>>>(p, Wo, bo, out);

    (void)in_sizes; (void)n_in; (void)out_size; (void)ws_size;
}

// Round 8
// 283.926 us; speedup vs baseline: 1.0405x; 1.0405x over previous
//
#include <hip/hip_runtime.h>
#include <hip/hip_bf16.h>
#include <math.h>

typedef __bf16 bf16_t;
typedef __bf16 bf16x8 __attribute__((ext_vector_type(8)));
typedef __bf16 bf16x2 __attribute__((ext_vector_type(2)));
typedef unsigned short ushort8v __attribute__((ext_vector_type(8)));
typedef float floatx4 __attribute__((ext_vector_type(4)));

static __device__ inline unsigned short f2bf_rne(float f) {
    unsigned int u = __builtin_bit_cast(unsigned int, f);
    unsigned int r = u + 0x7FFFu + ((u >> 16) & 1u);
    return (unsigned short)(r >> 16);
}
static __device__ inline bf16_t f2bf(float f) {
    return __builtin_bit_cast(bf16_t, f2bf_rne(f));
}

#if __has_builtin(__builtin_amdgcn_cvt_pk_bf16_f32)
static __device__ inline unsigned pk2bf(float a, float b) {
    bf16x2 v = __builtin_amdgcn_cvt_pk_bf16_f32(a, b);
    return __builtin_bit_cast(unsigned, v);
}
#else
static __device__ inline unsigned pk2bf(float a, float b) {
    return (unsigned)f2bf_rne(a) | ((unsigned)f2bf_rne(b) << 16);
}
#endif

#if __has_builtin(__builtin_amdgcn_exp2f)
#define EXP2F __builtin_amdgcn_exp2f
#else
#define EXP2F exp2f
#endif

static __device__ inline void store_c(float* C, size_t i, float v) { C[i] = v; }
static __device__ inline void store_c(bf16_t* C, size_t i, float v) { C[i] = f2bf(v); }

// convert 8 fp32 -> bf16x8 store (coalesced helper for bulk converts)
static __device__ inline void cvt8(const float* src, bf16_t* dst, size_t idx) {
    float4 a = *(const float4*)(src + idx);
    float4 c = *(const float4*)(src + idx + 4);
    ushort8v u;
    u[0] = f2bf_rne(a.x); u[1] = f2bf_rne(a.y); u[2] = f2bf_rne(a.z); u[3] = f2bf_rne(a.w);
    u[4] = f2bf_rne(c.x); u[5] = f2bf_rne(c.y); u[6] = f2bf_rne(c.z); u[7] = f2bf_rne(c.w);
    *(ushort8v*)(dst + idx) = u;
}

// ---------------------------------------------------------------------------
// Pure-bf16 GEMM body: C = A[M,K]*B[N,K]^T (+bias_col)(+bias_row).
// TM=128, TN=64, BK=32; LDS stride 68 (measured zero-conflict).
// ---------------------------------------------------------------------------
template <typename TC>
__device__ inline void gemm_body(
    const bf16_t* __restrict__ A, int lda,
    const bf16_t* __restrict__ B, int ldb,
    const float* __restrict__ bias_col, const float* __restrict__ bias_row,
    TC* __restrict__ C, int ldc, int K, int m0, int n0)
{
    __shared__ bf16_t As[128 * 68];
    __shared__ bf16_t Bs[64 * 68];

    const int tid = threadIdx.x;
    const int lane = tid & 63, wave = tid >> 6;
    const int wm = wave & 1, wn = wave >> 1;
    const int lo16 = lane & 15, quad = lane >> 4;
    const int sr = tid >> 2, sc = (tid & 3) * 8;

    floatx4 acc[4][2] = {};

    for (int k0 = 0; k0 < K; k0 += 32) {
        bf16x8 a0 = *(const bf16x8*)(A + (size_t)(m0 + sr) * lda + k0 + sc);
        bf16x8 a1 = *(const bf16x8*)(A + (size_t)(m0 + 64 + sr) * lda + k0 + sc);
        bf16x8 b0 = *(const bf16x8*)(B + (size_t)(n0 + sr) * ldb + k0 + sc);
        __syncthreads();
        *(bf16x8*)(&As[sr * 68 + sc]) = a0;
        *(bf16x8*)(&As[(64 + sr) * 68 + sc]) = a1;
        *(bf16x8*)(&Bs[sr * 68 + sc]) = b0;
        __syncthreads();

        bf16x8 af[4], bfv[2];
#pragma unroll
        for (int mt = 0; mt < 4; ++mt)
            af[mt] = *(const bf16x8*)(&As[(wm * 64 + mt * 16 + lo16) * 68 + quad * 8]);
#pragma unroll
        for (int nt = 0; nt < 2; ++nt)
            bfv[nt] = *(const bf16x8*)(&Bs[(wn * 32 + nt * 16 + lo16) * 68 + quad * 8]);
#pragma unroll
        for (int mt = 0; mt < 4; ++mt)
#pragma unroll
            for (int nt = 0; nt < 2; ++nt)
                acc[mt][nt] = __builtin_amdgcn_mfma_f32_16x16x32_bf16(
                    af[mt], bfv[nt], acc[mt][nt], 0, 0, 0);
    }

#pragma unroll
    for (int nt = 0; nt < 2; ++nt) {
        const int gn = n0 + wn * 32 + nt * 16 + lo16;
        const float bc = bias_col ? bias_col[gn] : 0.f;
#pragma unroll
        for (int mt = 0; mt < 4; ++mt) {
#pragma unroll
            for (int r = 0; r < 4; ++r) {
                const int gm = m0 + wm * 64 + mt * 16 + quad * 4 + r;
                float v = acc[mt][nt][r] + bc;
                if (bias_row) v += bias_row[gm];
                store_c(C, (size_t)gm * ldc + gn, v);
            }
        }
    }
}

// Bulk fp32->bf16 of q/k/v inputs and the 4 weight matrices. 8192 elems/block.
__global__ __launch_bounds__(256) void prep(
    const float* __restrict__ query, const float* __restrict__ key, const float* __restrict__ value,
    const float* __restrict__ Wq, const float* __restrict__ Wk,
    const float* __restrict__ Wv, const float* __restrict__ Wo,
    bf16_t* qB, bf16_t* kB, bf16_t* vB,
    bf16_t* wqB, bf16_t* wkB, bf16_t* wvB, bf16_t* woB)
{
    const int b = blockIdx.x;
    const float* src; bf16_t* dst; size_t base;
    if      (b < 256) { src = query; dst = qB;  base = (size_t)b * 8192; }
    else if (b < 512) { src = key;   dst = kB;  base = (size_t)(b - 256) * 8192; }
    else if (b < 768) { src = value; dst = vB;  base = (size_t)(b - 512) * 8192; }
    else if (b < 800) { src = Wq;    dst = wqB; base = (size_t)(b - 768) * 8192; }
    else if (b < 832) { src = Wk;    dst = wkB; base = (size_t)(b - 800) * 8192; }
    else if (b < 864) { src = Wv;    dst = wvB; base = (size_t)(b - 832) * 8192; }
    else              { src = Wo;    dst = woB; base = (size_t)(b - 864) * 8192; }
#pragma unroll
    for (int it = 0; it < 4; ++it)
        cvt8(src, dst, base + (size_t)it * 2048 + threadIdx.x * 8);
}

// Fused: 0-255 q-proj, 256-511 k-proj, 512-767 vt-proj, 768.. sg fp32->bf16.
__global__ __launch_bounds__(256) void proj_qkv(
    const bf16_t* __restrict__ qB, const bf16_t* __restrict__ wqB, const float* __restrict__ bq,
    const bf16_t* __restrict__ kB, const bf16_t* __restrict__ wkB, const float* __restrict__ bk,
    const bf16_t* __restrict__ wvB, const bf16_t* __restrict__ vB, const float* __restrict__ bv,
    const float* __restrict__ sg, bf16_t* __restrict__ sgb,
    bf16_t* __restrict__ q, bf16_t* __restrict__ k, bf16_t* __restrict__ vt)
{
    const int b = blockIdx.x;
    if (b >= 768) {  // sg convert: 8192 elems/block, 2048 blocks
        const size_t base = (size_t)(b - 768) * 8192;
#pragma unroll
        for (int it = 0; it < 4; ++it)
            cvt8(sg, sgb, base + (size_t)it * 2048 + threadIdx.x * 8);
        return;
    }
    const bf16_t *A, *B;
    const float *bc = nullptr, *br = nullptr;
    bf16_t* C;
    int ldc = 512, m0, n0;
    if (b < 512) {
        int i = b & 255, x = i & 7, t = i >> 3;
        n0 = (t & 7) * 64;
        m0 = ((t >> 3) * 8 + x) * 128;
        if (b < 256) { A = qB; B = wqB; bc = bq; C = q; }
        else         { A = kB; B = wkB; bc = bk; C = k; }
    } else {
        int i = b - 512;
        n0 = (i & 63) * 64;
        m0 = (i >> 6) * 128;
        A = wvB; B = vB; br = bv; C = vt; ldc = 4096;
    }
    gemm_body<bf16_t>(A, 512, B, 512, bc, br, C, ldc, 512, m0, n0);
}

// sgconv: bf16 x bf16, TM=TN=128, BK=32, 4-way K-split (grid 512).
__global__ __launch_bounds__(256) void sgconv_gemm(
    const bf16_t* __restrict__ sgb, const bf16_t* __restrict__ aot,
    float* __restrict__ part)
{
    const int i = blockIdx.x & 127;
    const int kb = blockIdx.x >> 7;
    const int ms = i & 31, ns = i >> 5;
    const int m0 = ms * 128, n0 = ns * 128;
    const int kbase = kb * 1024;

    __shared__ bf16_t As[128 * 68];
    __shared__ bf16_t Bs[128 * 68];

    const int tid = threadIdx.x;
    const int lane = tid & 63, wave = tid >> 6;
    const int wm = wave & 1, wn = wave >> 1;
    const int lo16 = lane & 15, quad = lane >> 4;
    const int sr = tid >> 1, sc = (tid & 1) * 16;

    const bf16_t* asrc = sgb + (size_t)(m0 + sr) * 4096 + kbase + sc;
    const bf16_t* bsrc = aot + (size_t)(n0 + sr) * 4096 + kbase + sc;

    floatx4 acc[4][4] = {};

    for (int k0 = 0; k0 < 1024; k0 += 32) {
        bf16x8 a0 = *(const bf16x8*)(asrc + k0);
        bf16x8 a1 = *(const bf16x8*)(asrc + k0 + 8);
        bf16x8 b0 = *(const bf16x8*)(bsrc + k0);
        bf16x8 b1 = *(const bf16x8*)(bsrc + k0 + 8);
        __syncthreads();
        *(bf16x8*)(&As[sr * 68 + sc]) = a0;
        *(bf16x8*)(&As[sr * 68 + sc + 8]) = a1;
        *(bf16x8*)(&Bs[sr * 68 + sc]) = b0;
        *(bf16x8*)(&Bs[sr * 68 + sc + 8]) = b1;
        __syncthreads();

        bf16x8 af[4], bfv[4];
#pragma unroll
        for (int mt = 0; mt < 4; ++mt)
            af[mt] = *(const bf16x8*)(&As[(wm * 64 + mt * 16 + lo16) * 68 + quad * 8]);
#pragma unroll
        for (int nt = 0; nt < 4; ++nt)
            bfv[nt] = *(const bf16x8*)(&Bs[(wn * 64 + nt * 16 + lo16) * 68 + quad * 8]);
#pragma unroll
        for (int mt = 0; mt < 4; ++mt)
#pragma unroll
            for (int nt = 0; nt < 4; ++nt)
                acc[mt][nt] = __builtin_amdgcn_mfma_f32_16x16x32_bf16(
                    af[mt], bfv[nt], acc[mt][nt], 0, 0, 0);
    }

    float* pw = part + (size_t)kb * (4096 * 512);
#pragma unroll
    for (int mt = 0; mt < 4; ++mt)
#pragma unroll
        for (int r = 0; r < 4; ++r) {
            const int gm = m0 + wm * 64 + mt * 16 + quad * 4 + r;
#pragma unroll
            for (int nt = 0; nt < 4; ++nt)
                pw[(size_t)gm * 512 + n0 + wn * 64 + nt * 16 + lo16] = acc[mt][nt][r];
        }
}

// sum 4 fp32 partials -> bf16 o2 (one pass, coalesced)
__global__ __launch_bounds__(256) void part_reduce(
    const float* __restrict__ p, bf16_t* __restrict__ o2)
{
    const size_t S = (size_t)4096 * 512;
    const size_t idx = ((size_t)blockIdx.x * 256 + threadIdx.x) * 8;
    ushort8v u;
#pragma unroll
    for (int half = 0; half < 2; ++half) {
        float4 s = *(const float4*)(p + idx + half * 4);
#pragma unroll
        for (int kb = 1; kb < 4; ++kb) {
            float4 t = *(const float4*)(p + kb * S + idx + half * 4);
            s.x += t.x; s.y += t.y; s.z += t.z; s.w += t.w;
        }
        u[half * 4 + 0] = f2bf_rne(s.x);
        u[half * 4 + 1] = f2bf_rne(s.y);
        u[half * 4 + 2] = f2bf_rne(s.z);
        u[half * 4 + 3] = f2bf_rne(s.w);
    }
    *(ushort8v*)(o2 + idx) = u;
}

// out = o2 @ Wo^T + bo   (all-bf16 GEMM, fp32 store)
__global__ __launch_bounds__(256) void out_proj(
    const bf16_t* __restrict__ o2, const bf16_t* __restrict__ woB,
    const float* __restrict__ bo, float* __restrict__ out)
{
    const int i = blockIdx.x, x = i & 7, t = i >> 3;
    const int n0 = (t & 7) * 64, m0 = ((t >> 3) * 8 + x) * 128;
    gemm_body<float>(o2, 512, woB, 512, bo, nullptr, out, 512, 512, m0, n0);
}

// ---------------------------------------------------------------------------
// Flash attention v5: stride-68 LDS (0-conflict), cvt_pk + exp2, VALU
// denominator accumulation (ones-MFMA reverted: it sat on the per-wave
// MFMA issue chain and cost +14% in r7).
// ---------------------------------------------------------------------------
__global__ __launch_bounds__(256, 4) void flash_attn(
    const bf16_t* __restrict__ q, const bf16_t* __restrict__ kk,
    const bf16_t* __restrict__ vt, float* __restrict__ op,
    float* __restrict__ lp, float scale2 /* scale*log2(e) */)
{
    const int N = 4096, D = 512;
    const int h   = blockIdx.x & 7;
    const int qb  = (blockIdx.x >> 3) & 31;
    const int qtr = blockIdx.x >> 8;
    const int t0  = qtr * 1024;

    const int tid = threadIdx.x;
    const int w = tid >> 6, lane = tid & 63;
    const int lo16 = lane & 15, quad = lane >> 4;

    __shared__ bf16_t Ks[64 * 68];
    __shared__ bf16_t Vs[64 * 68];
    __shared__ bf16_t Ps[4][32 * 68];

    const bf16_t* qp = q + (size_t)(qb * 128 + w * 32 + lo16) * D + h * 64 + quad * 8;
    bf16x8 qf[2][2];
    qf[0][0] = *(const bf16x8*)qp;
    qf[0][1] = *(const bf16x8*)(qp + 32);
    qf[1][0] = *(const bf16x8*)(qp + 16 * D);
    qf[1][1] = *(const bf16x8*)(qp + 16 * D + 32);

    const int srow = tid >> 2, sc = (tid & 3) * 16;
    const bf16_t* ksrc = kk + (size_t)(t0 + srow) * D + h * 64 + sc;
    const bf16_t* vsrc = vt + (size_t)(h * 64 + srow) * N + t0 + sc;
    bf16_t* kdst = &Ks[srow * 68 + sc];
    bf16_t* vdst = &Vs[srow * 68 + sc];

    floatx4 o[4][2] = {};
    float l[2] = {0.f, 0.f};

    bf16x8 kr0 = *(const bf16x8*)ksrc;
    bf16x8 kr1 = *(const bf16x8*)(ksrc + 8);
    bf16x8 vr0 = *(const bf16x8*)vsrc;
    bf16x8 vr1 = *(const bf16x8*)(vsrc + 8);

    for (int it = 0; it < 16; ++it) {
        __syncthreads();
        *(bf16x8*)kdst = kr0;  *(bf16x8*)(kdst + 8) = kr1;
        *(bf16x8*)vdst = vr0;  *(bf16x8*)(vdst + 8) = vr1;
        __syncthreads();
        if (it < 15) {
            const bf16_t* kn = ksrc + (size_t)(it + 1) * 64 * D;
            const bf16_t* vn = vsrc + (it + 1) * 64;
            kr0 = *(const bf16x8*)kn;  kr1 = *(const bf16x8*)(kn + 8);
            vr0 = *(const bf16x8*)vn;  vr1 = *(const bf16x8*)(vn + 8);
        }

        // S^T = K·Q^T : D[m=tok][n=q]
        floatx4 s[4][2];
#pragma unroll
        for (int tt = 0; tt < 4; ++tt) {
            bf16x8 kf0 = *(const bf16x8*)(&Ks[(tt * 16 + lo16) * 68 + quad * 8]);
            bf16x8 kf1 = *(const bf16x8*)(&Ks[(tt * 16 + lo16) * 68 + 32 + quad * 8]);
#pragma unroll
            for (int qt = 0; qt < 2; ++qt) {
                floatx4 a = {};
                a = __builtin_amdgcn_mfma_f32_16x16x32_bf16(kf0, qf[qt][0], a, 0, 0, 0);
                a = __builtin_amdgcn_mfma_f32_16x16x32_bf16(kf1, qf[qt][1], a, 0, 0, 0);
                s[tt][qt] = a;
            }
        }
        // exp2 + VALU row-sum accumulation + packed b64 P writes
#pragma unroll
        for (int tt = 0; tt < 4; ++tt)
#pragma unroll
            for (int qt = 0; qt < 2; ++qt) {
                float e0 = EXP2F(s[tt][qt][0] * scale2);
                float e1 = EXP2F(s[tt][qt][1] * scale2);
                float e2 = EXP2F(s[tt][qt][2] * scale2);
                float e3 = EXP2F(s[tt][qt][3] * scale2);
                l[qt] += (e0 + e1) + (e2 + e3);
                uint2 pk;
                pk.x = pk2bf(e0, e1);
                pk.y = pk2bf(e2, e3);
                *(uint2*)(&Ps[w][(qt * 16 + lo16) * 68 + tt * 16 + quad * 4]) = pk;
            }
        // PV: o[dim][q] += V·P^T
#pragma unroll
        for (int ks = 0; ks < 2; ++ks) {
            bf16x8 pf0 = *(const bf16x8*)(&Ps[w][lo16 * 68 + ks * 32 + quad * 8]);
            bf16x8 pf1 = *(const bf16x8*)(&Ps[w][(16 + lo16) * 68 + ks * 32 + quad * 8]);
#pragma unroll
            for (int t = 0; t < 4; ++t) {
                bf16x8 vf = *(const bf16x8*)(&Vs[(t * 16 + lo16) * 68 + ks * 32 + quad * 8]);
                o[t][0] = __builtin_amdgcn_mfma_f32_16x16x32_bf16(vf, pf0, o[t][0], 0, 0, 0);
                o[t][1] = __builtin_amdgcn_mfma_f32_16x16x32_bf16(vf, pf1, o[t][1], 0, 0, 0);
            }
        }
    }

    // reduce l across the 4 quads (each lane holds toks of its quad rows)
#pragma unroll
    for (int qt = 0; qt < 2; ++qt) {
        l[qt] += __shfl_xor(l[qt], 16);
        l[qt] += __shfl_xor(l[qt], 32);
    }

    const int g = blockIdx.x & 255;
    float* opw = op + ((size_t)qtr * 256 + g) * 8192;
#pragma unroll
    for (int t = 0; t < 4; ++t)
#pragma unroll
        for (int pt = 0; pt < 2; ++pt)
#pragma unroll
            for (int r = 0; r < 4; ++r)
                opw[(t * 16 + quad * 4 + r) * 128 + w * 32 + pt * 16 + lo16] = o[t][pt][r];

    if (quad == 0) {
        float* lpw = lp + ((size_t)qtr * 256 + g) * 128;
        lpw[w * 32 + lo16] = l[0];
        lpw[w * 32 + 16 + lo16] = l[1];
    }
}

__global__ __launch_bounds__(256) void attn_combine(
    const float* __restrict__ op, const float* __restrict__ lp, bf16_t* __restrict__ aot)
{
    const int g = blockIdx.x;
    const int h = g & 7, qb = g >> 3;
    const int tid = threadIdx.x;
    __shared__ float ls[128];
    if (tid < 128) {
        float s = 0.f;
#pragma unroll
        for (int qtr = 0; qtr < 4; ++qtr)
            s += lp[((size_t)qtr * 256 + g) * 128 + tid];
        ls[tid] = 1.0f / s;
    }
    __syncthreads();
    const float* b0 = op + (size_t)g * 8192;
    const size_t QS = (size_t)256 * 8192;
#pragma unroll 4
    for (int i = 0; i < 32; ++i) {
        int idx = i * 256 + tid;
        float v = b0[idx] + b0[QS + idx] + b0[2 * QS + idx] + b0[3 * QS + idx];
        int dim = idx >> 7, qc = idx & 127;
        aot[(size_t)(h * 64 + dim) * 4096 + qb * 128 + qc] = f2bf(v * ls[qc]);
    }
}

extern "C" void kernel_launch(void* const* d_in, const int* in_sizes, int n_in,
                              void* d_out, int out_size, void* d_ws, size_t ws_size,
                              hipStream_t stream)
{
    const int N = 4096, D = 512;
    const float* query = (const float*)d_in[0];
    const float* key_t = (const float*)d_in[1];
    const float* value = (const float*)d_in[2];
    const float* Wq = (const float*)d_in[3];
    const float* bq = (const float*)d_in[4];
    const float* Wk = (const float*)d_in[5];
    const float* bk = (const float*)d_in[6];
    const float* Wv = (const float*)d_in[7];
    const float* bv = (const float*)d_in[8];
    const float* Wo = (const float*)d_in[9];
    const float* bo = (const float*)d_in[10];
    const float* sg = (const float*)d_in[11];
    float* out = (float*)d_out;

    const size_t ND = (size_t)N * D;        // 2.1M elems
    const size_t DD = (size_t)D * D;        // 262k elems

    char* base = (char*)d_ws;
    bf16_t* q    = (bf16_t*)base;                       // 4 MB
    bf16_t* kk   = q   + ND;                            // 4 MB
    bf16_t* vt   = kk  + ND;                            // 4 MB
    bf16_t* aot  = vt  + ND;                            // 4 MB
    bf16_t* sgb  = aot + ND;                            // 33.5 MB
    char* regA   = (char*)(sgb + (size_t)N * N);        // 33.5 MB shared region
    // region A, phase 1: prep inputs (qB kB vB wqB wkB wvB)
    bf16_t* qB   = (bf16_t*)regA;
    bf16_t* kB   = qB + ND;
    bf16_t* vB   = kB + ND;
    bf16_t* wqB  = vB + ND;
    bf16_t* wkB  = wqB + DD;
    bf16_t* wvB  = wkB + DD;
    // region A, phase 2: flash partials op; phase 3: sgconv partials p
    float* op    = (float*)regA;                        // 4*256*8192 fp32 = 33.5 MB
    float* p     = (float*)regA;                        // 4*N*D fp32 = 33.5 MB
    char* tail   = regA + (size_t)4 * 256 * 8192 * 4;
    float*  lp   = (float*)tail;                        // 512 KB
    bf16_t* woB  = (bf16_t*)(lp + (size_t)4 * 256 * 128);  // 0.5 MB
    bf16_t* o2   = woB + DD;                            // 4 MB

    const dim3 blk(256);

    prep<<<896, blk, 0, stream>>>(query, key_t, value, Wq, Wk, Wv, Wo,
                                  qB, kB, vB, wqB, wkB, wvB, woB);

    proj_qkv<<<2816, blk, 0, stream>>>(qB, wqB, bq, kB, wkB, bk,
                                       wvB, vB, bv, sg, sgb, q, kk, vt);

    const float scale2 = 1.4426950408889634f / sqrtf((float)D);
    flash_attn<<<1024, blk, 0, stream>>>(q, kk, vt, op, lp, scale2);
    attn_combine<<<256, blk, 0, stream>>>(op, lp, aot);

    sgconv_gemm<<<512, blk, 0, stream>>>(sgb, aot, p);
    part_reduce<<<1024, blk, 0, stream>>>(p, o2);
    out_proj<<<256, blk, 0, stream>>>(o2, woB, bo, out);

    (void)in_sizes; (void)n_in; (void)out_size; (void)ws_size;
}

// Round 9
// 262.862 us; speedup vs baseline: 1.1239x; 1.0801x over previous
//
#include <hip/hip_runtime.h>
#include <hip/hip_bf16.h>
#include <math.h>

typedef __bf16 bf16_t;
typedef __bf16 bf16x8 __attribute__((ext_vector_type(8)));
typedef unsigned short ushort8v __attribute__((ext_vector_type(8)));
typedef float floatx4 __attribute__((ext_vector_type(4)));

static __device__ inline unsigned short f2bf_rne(float f) {
    unsigned int u = __builtin_bit_cast(unsigned int, f);
    unsigned int r = u + 0x7FFFu + ((u >> 16) & 1u);
    return (unsigned short)(r >> 16);
}
static __device__ inline bf16_t f2bf(float f) {
    return __builtin_bit_cast(bf16_t, f2bf_rne(f));
}

static __device__ inline void store_c(float* C, size_t i, float v) { C[i] = v; }
static __device__ inline void store_c(bf16_t* C, size_t i, float v) { C[i] = f2bf(v); }

// convert 8 fp32 -> bf16x8 store (coalesced helper for bulk converts)
static __device__ inline void cvt8(const float* src, bf16_t* dst, size_t idx) {
    float4 a = *(const float4*)(src + idx);
    float4 c = *(const float4*)(src + idx + 4);
    ushort8v u;
    u[0] = f2bf_rne(a.x); u[1] = f2bf_rne(a.y); u[2] = f2bf_rne(a.z); u[3] = f2bf_rne(a.w);
    u[4] = f2bf_rne(c.x); u[5] = f2bf_rne(c.y); u[6] = f2bf_rne(c.z); u[7] = f2bf_rne(c.w);
    *(ushort8v*)(dst + idx) = u;
}

// ---------------------------------------------------------------------------
// Pure-bf16 GEMM body: C = A[M,K]*B[N,K]^T (+bias_col)(+bias_row).
// TM=128, TN=64, BK=32; LDS stride 68.
// ---------------------------------------------------------------------------
template <typename TC>
__device__ inline void gemm_body(
    const bf16_t* __restrict__ A, int lda,
    const bf16_t* __restrict__ B, int ldb,
    const float* __restrict__ bias_col, const float* __restrict__ bias_row,
    TC* __restrict__ C, int ldc, int K, int m0, int n0)
{
    __shared__ bf16_t As[128 * 68];
    __shared__ bf16_t Bs[64 * 68];

    const int tid = threadIdx.x;
    const int lane = tid & 63, wave = tid >> 6;
    const int wm = wave & 1, wn = wave >> 1;
    const int lo16 = lane & 15, quad = lane >> 4;
    const int sr = tid >> 2, sc = (tid & 3) * 8;

    floatx4 acc[4][2] = {};

    for (int k0 = 0; k0 < K; k0 += 32) {
        bf16x8 a0 = *(const bf16x8*)(A + (size_t)(m0 + sr) * lda + k0 + sc);
        bf16x8 a1 = *(const bf16x8*)(A + (size_t)(m0 + 64 + sr) * lda + k0 + sc);
        bf16x8 b0 = *(const bf16x8*)(B + (size_t)(n0 + sr) * ldb + k0 + sc);
        __syncthreads();
        *(bf16x8*)(&As[sr * 68 + sc]) = a0;
        *(bf16x8*)(&As[(64 + sr) * 68 + sc]) = a1;
        *(bf16x8*)(&Bs[sr * 68 + sc]) = b0;
        __syncthreads();

        bf16x8 af[4], bfv[2];
#pragma unroll
        for (int mt = 0; mt < 4; ++mt)
            af[mt] = *(const bf16x8*)(&As[(wm * 64 + mt * 16 + lo16) * 68 + quad * 8]);
#pragma unroll
        for (int nt = 0; nt < 2; ++nt)
            bfv[nt] = *(const bf16x8*)(&Bs[(wn * 32 + nt * 16 + lo16) * 68 + quad * 8]);
#pragma unroll
        for (int mt = 0; mt < 4; ++mt)
#pragma unroll
            for (int nt = 0; nt < 2; ++nt)
                acc[mt][nt] = __builtin_amdgcn_mfma_f32_16x16x32_bf16(
                    af[mt], bfv[nt], acc[mt][nt], 0, 0, 0);
    }

#pragma unroll
    for (int nt = 0; nt < 2; ++nt) {
        const int gn = n0 + wn * 32 + nt * 16 + lo16;
        const float bc = bias_col ? bias_col[gn] : 0.f;
#pragma unroll
        for (int mt = 0; mt < 4; ++mt) {
#pragma unroll
            for (int r = 0; r < 4; ++r) {
                const int gm = m0 + wm * 64 + mt * 16 + quad * 4 + r;
                float v = acc[mt][nt][r] + bc;
                if (bias_row) v += bias_row[gm];
                store_c(C, (size_t)gm * ldc + gn, v);
            }
        }
    }
}

// Bulk fp32->bf16 of q/k/v inputs and the 4 weight matrices. 8192 elems/block.
__global__ __launch_bounds__(256) void prep(
    const float* __restrict__ query, const float* __restrict__ key, const float* __restrict__ value,
    const float* __restrict__ Wq, const float* __restrict__ Wk,
    const float* __restrict__ Wv, const float* __restrict__ Wo,
    bf16_t* qB, bf16_t* kB, bf16_t* vB,
    bf16_t* wqB, bf16_t* wkB, bf16_t* wvB, bf16_t* woB)
{
    const int b = blockIdx.x;
    const float* src; bf16_t* dst; size_t base;
    if      (b < 256) { src = query; dst = qB;  base = (size_t)b * 8192; }
    else if (b < 512) { src = key;   dst = kB;  base = (size_t)(b - 256) * 8192; }
    else if (b < 768) { src = value; dst = vB;  base = (size_t)(b - 512) * 8192; }
    else if (b < 800) { src = Wq;    dst = wqB; base = (size_t)(b - 768) * 8192; }
    else if (b < 832) { src = Wk;    dst = wkB; base = (size_t)(b - 800) * 8192; }
    else if (b < 864) { src = Wv;    dst = wvB; base = (size_t)(b - 832) * 8192; }
    else              { src = Wo;    dst = woB; base = (size_t)(b - 864) * 8192; }
#pragma unroll
    for (int it = 0; it < 4; ++it)
        cvt8(src, dst, base + (size_t)it * 2048 + threadIdx.x * 8);
}

// Fused: 0-255 q-proj, 256-511 k-proj, 512-767 vt-proj, 768.. sg fp32->bf16.
__global__ __launch_bounds__(256) void proj_qkv(
    const bf16_t* __restrict__ qB, const bf16_t* __restrict__ wqB, const float* __restrict__ bq,
    const bf16_t* __restrict__ kB, const bf16_t* __restrict__ wkB, const float* __restrict__ bk,
    const bf16_t* __restrict__ wvB, const bf16_t* __restrict__ vB, const float* __restrict__ bv,
    const float* __restrict__ sg, bf16_t* __restrict__ sgb,
    bf16_t* __restrict__ q, bf16_t* __restrict__ k, bf16_t* __restrict__ vt)
{
    const int b = blockIdx.x;
    if (b >= 768) {  // sg convert: 8192 elems/block, 2048 blocks
        const size_t base = (size_t)(b - 768) * 8192;
#pragma unroll
        for (int it = 0; it < 4; ++it)
            cvt8(sg, sgb, base + (size_t)it * 2048 + threadIdx.x * 8);
        return;
    }
    const bf16_t *A, *B;
    const float *bc = nullptr, *br = nullptr;
    bf16_t* C;
    int ldc = 512, m0, n0;
    if (b < 512) {
        int i = b & 255, x = i & 7, t = i >> 3;
        n0 = (t & 7) * 64;
        m0 = ((t >> 3) * 8 + x) * 128;
        if (b < 256) { A = qB; B = wqB; bc = bq; C = q; }
        else         { A = kB; B = wkB; bc = bk; C = k; }
    } else {
        int i = b - 512;
        n0 = (i & 63) * 64;
        m0 = (i >> 6) * 128;
        A = wvB; B = vB; br = bv; C = vt; ldc = 4096;
    }
    gemm_body<bf16_t>(A, 512, B, 512, bc, br, C, ldc, 512, m0, n0);
}

// sgconv: bf16 x bf16, TM=TN=128, BK=32, 4-way K-split (grid 512).
__global__ __launch_bounds__(256) void sgconv_gemm(
    const bf16_t* __restrict__ sgb, const bf16_t* __restrict__ aot,
    float* __restrict__ part)
{
    const int i = blockIdx.x & 127;
    const int kb = blockIdx.x >> 7;
    const int ms = i & 31, ns = i >> 5;
    const int m0 = ms * 128, n0 = ns * 128;
    const int kbase = kb * 1024;

    __shared__ bf16_t As[128 * 68];
    __shared__ bf16_t Bs[128 * 68];

    const int tid = threadIdx.x;
    const int lane = tid & 63, wave = tid >> 6;
    const int wm = wave & 1, wn = wave >> 1;
    const int lo16 = lane & 15, quad = lane >> 4;
    const int sr = tid >> 1, sc = (tid & 1) * 16;

    const bf16_t* asrc = sgb + (size_t)(m0 + sr) * 4096 + kbase + sc;
    const bf16_t* bsrc = aot + (size_t)(n0 + sr) * 4096 + kbase + sc;

    floatx4 acc[4][4] = {};

    for (int k0 = 0; k0 < 1024; k0 += 32) {
        bf16x8 a0 = *(const bf16x8*)(asrc + k0);
        bf16x8 a1 = *(const bf16x8*)(asrc + k0 + 8);
        bf16x8 b0 = *(const bf16x8*)(bsrc + k0);
        bf16x8 b1 = *(const bf16x8*)(bsrc + k0 + 8);
        __syncthreads();
        *(bf16x8*)(&As[sr * 68 + sc]) = a0;
        *(bf16x8*)(&As[sr * 68 + sc + 8]) = a1;
        *(bf16x8*)(&Bs[sr * 68 + sc]) = b0;
        *(bf16x8*)(&Bs[sr * 68 + sc + 8]) = b1;
        __syncthreads();

        bf16x8 af[4], bfv[4];
#pragma unroll
        for (int mt = 0; mt < 4; ++mt)
            af[mt] = *(const bf16x8*)(&As[(wm * 64 + mt * 16 + lo16) * 68 + quad * 8]);
#pragma unroll
        for (int nt = 0; nt < 4; ++nt)
            bfv[nt] = *(const bf16x8*)(&Bs[(wn * 64 + nt * 16 + lo16) * 68 + quad * 8]);
#pragma unroll
        for (int mt = 0; mt < 4; ++mt)
#pragma unroll
            for (int nt = 0; nt < 4; ++nt)
                acc[mt][nt] = __builtin_amdgcn_mfma_f32_16x16x32_bf16(
                    af[mt], bfv[nt], acc[mt][nt], 0, 0, 0);
    }

    float* pw = part + (size_t)kb * (4096 * 512);
#pragma unroll
    for (int mt = 0; mt < 4; ++mt)
#pragma unroll
        for (int r = 0; r < 4; ++r) {
            const int gm = m0 + wm * 64 + mt * 16 + quad * 4 + r;
#pragma unroll
            for (int nt = 0; nt < 4; ++nt)
                pw[(size_t)gm * 512 + n0 + wn * 64 + nt * 16 + lo16] = acc[mt][nt][r];
        }
}

// sum 4 fp32 partials -> bf16 o2 (one pass, coalesced)
__global__ __launch_bounds__(256) void part_reduce(
    const float* __restrict__ p, bf16_t* __restrict__ o2)
{
    const size_t S = (size_t)4096 * 512;
    const size_t idx = ((size_t)blockIdx.x * 256 + threadIdx.x) * 8;
    ushort8v u;
#pragma unroll
    for (int half = 0; half < 2; ++half) {
        float4 s = *(const float4*)(p + idx + half * 4);
#pragma unroll
        for (int kb = 1; kb < 4; ++kb) {
            float4 t = *(const float4*)(p + kb * S + idx + half * 4);
            s.x += t.x; s.y += t.y; s.z += t.z; s.w += t.w;
        }
        u[half * 4 + 0] = f2bf_rne(s.x);
        u[half * 4 + 1] = f2bf_rne(s.y);
        u[half * 4 + 2] = f2bf_rne(s.z);
        u[half * 4 + 3] = f2bf_rne(s.w);
    }
    *(ushort8v*)(o2 + idx) = u;
}

// out = o2 @ Wo^T + bo   (all-bf16 GEMM, fp32 store)
__global__ __launch_bounds__(256) void out_proj(
    const bf16_t* __restrict__ o2, const bf16_t* __restrict__ woB,
    const float* __restrict__ bo, float* __restrict__ out)
{
    const int i = blockIdx.x, x = i & 7, t = i >> 3;
    const int n0 = (t & 7) * 64, m0 = ((t >> 3) * 8 + x) * 128;
    gemm_body<float>(o2, 512, woB, 512, bo, nullptr, out, 512, 512, m0, n0);
}

// ---------------------------------------------------------------------------
// Flash attention — r6 body verbatim (best measured: 66.8 µs).
// stride-72 LDS, manual bf16 pack, __expf, VALU denominator accumulation.
// (r7/r8 "improvements" — stride-68, cvt_pk, exp2, ones-MFMA — all regressed;
//  the loop is bound by the P LDS round-trip chain, not VALU/conflicts.)
// ---------------------------------------------------------------------------
__global__ __launch_bounds__(256, 4) void flash_attn(
    const bf16_t* __restrict__ q, const bf16_t* __restrict__ kk,
    const bf16_t* __restrict__ vt, float* __restrict__ op,
    float* __restrict__ lp, float scale)
{
    const int N = 4096, D = 512;
    const int h   = blockIdx.x & 7;
    const int qb  = (blockIdx.x >> 3) & 31;
    const int qtr = blockIdx.x >> 8;
    const int t0  = qtr * 1024;

    const int tid = threadIdx.x;
    const int w = tid >> 6, lane = tid & 63;
    const int lo16 = lane & 15, quad = lane >> 4;

    __shared__ bf16_t Ks[64 * 72];
    __shared__ bf16_t Vs[64 * 72];
    __shared__ bf16_t Ps[4][32 * 72];

    const bf16_t* qp = q + (size_t)(qb * 128 + w * 32 + lo16) * D + h * 64 + quad * 8;
    bf16x8 qf[2][2];
    qf[0][0] = *(const bf16x8*)qp;
    qf[0][1] = *(const bf16x8*)(qp + 32);
    qf[1][0] = *(const bf16x8*)(qp + 16 * D);
    qf[1][1] = *(const bf16x8*)(qp + 16 * D + 32);

    const int srow = tid >> 2, sc = (tid & 3) * 16;
    const bf16_t* ksrc = kk + (size_t)(t0 + srow) * D + h * 64 + sc;
    const bf16_t* vsrc = vt + (size_t)(h * 64 + srow) * N + t0 + sc;
    bf16_t* kdst = &Ks[srow * 72 + sc];
    bf16_t* vdst = &Vs[srow * 72 + sc];

    floatx4 o[4][2] = {};
    float l[2] = {0.f, 0.f};

    bf16x8 kr0 = *(const bf16x8*)ksrc;
    bf16x8 kr1 = *(const bf16x8*)(ksrc + 8);
    bf16x8 vr0 = *(const bf16x8*)vsrc;
    bf16x8 vr1 = *(const bf16x8*)(vsrc + 8);

    for (int it = 0; it < 16; ++it) {
        __syncthreads();
        *(bf16x8*)kdst = kr0;  *(bf16x8*)(kdst + 8) = kr1;
        *(bf16x8*)vdst = vr0;  *(bf16x8*)(vdst + 8) = vr1;
        __syncthreads();
        if (it < 15) {
            const bf16_t* kn = ksrc + (size_t)(it + 1) * 64 * D;
            const bf16_t* vn = vsrc + (it + 1) * 64;
            kr0 = *(const bf16x8*)kn;  kr1 = *(const bf16x8*)(kn + 8);
            vr0 = *(const bf16x8*)vn;  vr1 = *(const bf16x8*)(vn + 8);
        }

        // S^T = K·Q^T : D[m=tok][n=q]
        floatx4 s[4][2];
#pragma unroll
        for (int tt = 0; tt < 4; ++tt) {
            bf16x8 kf0 = *(const bf16x8*)(&Ks[(tt * 16 + lo16) * 72 + quad * 8]);
            bf16x8 kf1 = *(const bf16x8*)(&Ks[(tt * 16 + lo16) * 72 + 32 + quad * 8]);
#pragma unroll
            for (int qt = 0; qt < 2; ++qt) {
                floatx4 a = {};
                a = __builtin_amdgcn_mfma_f32_16x16x32_bf16(kf0, qf[qt][0], a, 0, 0, 0);
                a = __builtin_amdgcn_mfma_f32_16x16x32_bf16(kf1, qf[qt][1], a, 0, 0, 0);
                s[tt][qt] = a;
            }
        }
        // exp + per-lane partial row sums + packed b64 P writes
#pragma unroll
        for (int tt = 0; tt < 4; ++tt)
#pragma unroll
            for (int qt = 0; qt < 2; ++qt) {
                float e0 = __expf(s[tt][qt][0] * scale);
                float e1 = __expf(s[tt][qt][1] * scale);
                float e2 = __expf(s[tt][qt][2] * scale);
                float e3 = __expf(s[tt][qt][3] * scale);
                l[qt] += (e0 + e1) + (e2 + e3);
                uint2 pk;
                pk.x = (unsigned)f2bf_rne(e0) | ((unsigned)f2bf_rne(e1) << 16);
                pk.y = (unsigned)f2bf_rne(e2) | ((unsigned)f2bf_rne(e3) << 16);
                *(uint2*)(&Ps[w][(qt * 16 + lo16) * 72 + tt * 16 + quad * 4]) = pk;
            }
        // PV: o[dim][q] += V·P^T
#pragma unroll
        for (int ks = 0; ks < 2; ++ks) {
            bf16x8 pf0 = *(const bf16x8*)(&Ps[w][lo16 * 72 + ks * 32 + quad * 8]);
            bf16x8 pf1 = *(const bf16x8*)(&Ps[w][(16 + lo16) * 72 + ks * 32 + quad * 8]);
#pragma unroll
            for (int t = 0; t < 4; ++t) {
                bf16x8 vf = *(const bf16x8*)(&Vs[(t * 16 + lo16) * 72 + ks * 32 + quad * 8]);
                o[t][0] = __builtin_amdgcn_mfma_f32_16x16x32_bf16(vf, pf0, o[t][0], 0, 0, 0);
                o[t][1] = __builtin_amdgcn_mfma_f32_16x16x32_bf16(vf, pf1, o[t][1], 0, 0, 0);
            }
        }
    }

    // reduce l across the 4 quads
#pragma unroll
    for (int qt = 0; qt < 2; ++qt) {
        l[qt] += __shfl_xor(l[qt], 16);
        l[qt] += __shfl_xor(l[qt], 32);
    }

    const int g = blockIdx.x & 255;
    float* opw = op + ((size_t)qtr * 256 + g) * 8192;
#pragma unroll
    for (int t = 0; t < 4; ++t)
#pragma unroll
        for (int pt = 0; pt < 2; ++pt)
#pragma unroll
            for (int r = 0; r < 4; ++r)
                opw[(t * 16 + quad * 4 + r) * 128 + w * 32 + pt * 16 + lo16] = o[t][pt][r];

    if (quad == 0) {
        float* lpw = lp + ((size_t)qtr * 256 + g) * 128;
        lpw[w * 32 + lo16] = l[0];
        lpw[w * 32 + 16 + lo16] = l[1];
    }
}

__global__ __launch_bounds__(256) void attn_combine(
    const float* __restrict__ op, const float* __restrict__ lp, bf16_t* __restrict__ aot)
{
    const int g = blockIdx.x;
    const int h = g & 7, qb = g >> 3;
    const int tid = threadIdx.x;
    __shared__ float ls[128];
    if (tid < 128) {
        float s = 0.f;
#pragma unroll
        for (int qtr = 0; qtr < 4; ++qtr)
            s += lp[((size_t)qtr * 256 + g) * 128 + tid];
        ls[tid] = 1.0f / s;
    }
    __syncthreads();
    const float* b0 = op + (size_t)g * 8192;
    const size_t QS = (size_t)256 * 8192;
#pragma unroll 4
    for (int i = 0; i < 32; ++i) {
        int idx = i * 256 + tid;
        float v = b0[idx] + b0[QS + idx] + b0[2 * QS + idx] + b0[3 * QS + idx];
        int dim = idx >> 7, qc = idx & 127;
        aot[(size_t)(h * 64 + dim) * 4096 + qb * 128 + qc] = f2bf(v * ls[qc]);
    }
}

extern "C" void kernel_launch(void* const* d_in, const int* in_sizes, int n_in,
                              void* d_out, int out_size, void* d_ws, size_t ws_size,
                              hipStream_t stream)
{
    const int N = 4096, D = 512;
    const float* query = (const float*)d_in[0];
    const float* key_t = (const float*)d_in[1];
    const float* value = (const float*)d_in[2];
    const float* Wq = (const float*)d_in[3];
    const float* bq = (const float*)d_in[4];
    const float* Wk = (const float*)d_in[5];
    const float* bk = (const float*)d_in[6];
    const float* Wv = (const float*)d_in[7];
    const float* bv = (const float*)d_in[8];
    const float* Wo = (const float*)d_in[9];
    const float* bo = (const float*)d_in[10];
    const float* sg = (const float*)d_in[11];
    float* out = (float*)d_out;

    const size_t ND = (size_t)N * D;
    const size_t DD = (size_t)D * D;

    char* base = (char*)d_ws;
    bf16_t* q    = (bf16_t*)base;
    bf16_t* kk   = q   + ND;
    bf16_t* vt   = kk  + ND;
    bf16_t* aot  = vt  + ND;
    bf16_t* sgb  = aot + ND;
    char* regA   = (char*)(sgb + (size_t)N * N);
    // region A, phase 1: prep inputs
    bf16_t* qB   = (bf16_t*)regA;
    bf16_t* kB   = qB + ND;
    bf16_t* vB   = kB + ND;
    bf16_t* wqB  = vB + ND;
    bf16_t* wkB  = wqB + DD;
    bf16_t* wvB  = wkB + DD;
    // region A, phase 2: flash partials op; phase 3: sgconv partials p
    float* op    = (float*)regA;
    float* p     = (float*)regA;
    char* tail   = regA + (size_t)4 * 256 * 8192 * 4;
    float*  lp   = (float*)tail;
    bf16_t* woB  = (bf16_t*)(lp + (size_t)4 * 256 * 128);
    bf16_t* o2   = woB + DD;

    const dim3 blk(256);

    prep<<<896, blk, 0, stream>>>(query, key_t, value, Wq, Wk, Wv, Wo,
                                  qB, kB, vB, wqB, wkB, wvB, woB);

    proj_qkv<<<2816, blk, 0, stream>>>(qB, wqB, bq, kB, wkB, bk,
                                       wvB, vB, bv, sg, sgb, q, kk, vt);

    const float scale = 1.0f / sqrtf((float)D);
    flash_attn<<<1024, blk, 0, stream>>>(q, kk, vt, op, lp, scale);
    attn_combine<<<256, blk, 0, stream>>>(op, lp, aot);

    sgconv_gemm<<<512, blk, 0, stream>>>(sgb, aot, p);
    part_reduce<<<1024, blk, 0, stream>>>(p, o2);
    out_proj<<<256, blk, 0, stream>>>(o2, woB, bo, out);

    (void)in_sizes; (void)n_in; (void)out_size; (void)ws_size;
}

// Round 10
// 252.687 us; speedup vs baseline: 1.1691x; 1.0403x over previous
//
#include <hip/hip_runtime.h>
#include <hip/hip_bf16.h>
#include <math.h>

typedef __bf16 bf16_t;
typedef __bf16 bf16x8 __attribute__((ext_vector_type(8)));
typedef unsigned short ushort8v __attribute__((ext_vector_type(8)));
typedef float floatx4 __attribute__((ext_vector_type(4)));

static __device__ inline unsigned short f2bf_rne(float f) {
    unsigned int u = __builtin_bit_cast(unsigned int, f);
    unsigned int r = u + 0x7FFFu + ((u >> 16) & 1u);
    return (unsigned short)(r >> 16);
}
static __device__ inline bf16_t f2bf(float f) {
    return __builtin_bit_cast(bf16_t, f2bf_rne(f));
}

static __device__ inline void store_c(float* C, size_t i, float v) { C[i] = v; }
static __device__ inline void store_c(bf16_t* C, size_t i, float v) { C[i] = f2bf(v); }

// convert 8 fp32 -> bf16x8 store
static __device__ inline void cvt8(const float* src, bf16_t* dst, size_t idx) {
    float4 a = *(const float4*)(src + idx);
    float4 c = *(const float4*)(src + idx + 4);
    ushort8v u;
    u[0] = f2bf_rne(a.x); u[1] = f2bf_rne(a.y); u[2] = f2bf_rne(a.z); u[3] = f2bf_rne(a.w);
    u[4] = f2bf_rne(c.x); u[5] = f2bf_rne(c.y); u[6] = f2bf_rne(c.z); u[7] = f2bf_rne(c.w);
    *(ushort8v*)(dst + idx) = u;
}

// ---------------------------------------------------------------------------
// Pure-bf16 GEMM body: C = A[M,K]*B[N,K]^T (+bias_col)(+bias_row).
// TM=128, TN=64, BK=32; LDS stride 68.
// ---------------------------------------------------------------------------
template <typename TC>
__device__ inline void gemm_body(
    const bf16_t* __restrict__ A, int lda,
    const bf16_t* __restrict__ B, int ldb,
    const float* __restrict__ bias_col, const float* __restrict__ bias_row,
    TC* __restrict__ C, int ldc, int K, int m0, int n0)
{
    __shared__ bf16_t As[128 * 68];
    __shared__ bf16_t Bs[64 * 68];

    const int tid = threadIdx.x;
    const int lane = tid & 63, wave = tid >> 6;
    const int wm = wave & 1, wn = wave >> 1;
    const int lo16 = lane & 15, quad = lane >> 4;
    const int sr = tid >> 2, sc = (tid & 3) * 8;

    floatx4 acc[4][2] = {};

    for (int k0 = 0; k0 < K; k0 += 32) {
        bf16x8 a0 = *(const bf16x8*)(A + (size_t)(m0 + sr) * lda + k0 + sc);
        bf16x8 a1 = *(const bf16x8*)(A + (size_t)(m0 + 64 + sr) * lda + k0 + sc);
        bf16x8 b0 = *(const bf16x8*)(B + (size_t)(n0 + sr) * ldb + k0 + sc);
        __syncthreads();
        *(bf16x8*)(&As[sr * 68 + sc]) = a0;
        *(bf16x8*)(&As[(64 + sr) * 68 + sc]) = a1;
        *(bf16x8*)(&Bs[sr * 68 + sc]) = b0;
        __syncthreads();

        bf16x8 af[4], bfv[2];
#pragma unroll
        for (int mt = 0; mt < 4; ++mt)
            af[mt] = *(const bf16x8*)(&As[(wm * 64 + mt * 16 + lo16) * 68 + quad * 8]);
#pragma unroll
        for (int nt = 0; nt < 2; ++nt)
            bfv[nt] = *(const bf16x8*)(&Bs[(wn * 32 + nt * 16 + lo16) * 68 + quad * 8]);
#pragma unroll
        for (int mt = 0; mt < 4; ++mt)
#pragma unroll
            for (int nt = 0; nt < 2; ++nt)
                acc[mt][nt] = __builtin_amdgcn_mfma_f32_16x16x32_bf16(
                    af[mt], bfv[nt], acc[mt][nt], 0, 0, 0);
    }

#pragma unroll
    for (int nt = 0; nt < 2; ++nt) {
        const int gn = n0 + wn * 32 + nt * 16 + lo16;
        const float bc = bias_col ? bias_col[gn] : 0.f;
#pragma unroll
        for (int mt = 0; mt < 4; ++mt) {
#pragma unroll
            for (int r = 0; r < 4; ++r) {
                const int gm = m0 + wm * 64 + mt * 16 + quad * 4 + r;
                float v = acc[mt][nt][r] + bc;
                if (bias_row) v += bias_row[gm];
                store_c(C, (size_t)gm * ldc + gn, v);
            }
        }
    }
}

// Bulk fp32->bf16 of q/k/v inputs and the 4 weight matrices. 8192 elems/block.
__global__ __launch_bounds__(256) void prep(
    const float* __restrict__ query, const float* __restrict__ key, const float* __restrict__ value,
    const float* __restrict__ Wq, const float* __restrict__ Wk,
    const float* __restrict__ Wv, const float* __restrict__ Wo,
    bf16_t* qB, bf16_t* kB, bf16_t* vB,
    bf16_t* wqB, bf16_t* wkB, bf16_t* wvB, bf16_t* woB)
{
    const int b = blockIdx.x;
    const float* src; bf16_t* dst; size_t base;
    if      (b < 256) { src = query; dst = qB;  base = (size_t)b * 8192; }
    else if (b < 512) { src = key;   dst = kB;  base = (size_t)(b - 256) * 8192; }
    else if (b < 768) { src = value; dst = vB;  base = (size_t)(b - 512) * 8192; }
    else if (b < 800) { src = Wq;    dst = wqB; base = (size_t)(b - 768) * 8192; }
    else if (b < 832) { src = Wk;    dst = wkB; base = (size_t)(b - 800) * 8192; }
    else if (b < 864) { src = Wv;    dst = wvB; base = (size_t)(b - 832) * 8192; }
    else              { src = Wo;    dst = woB; base = (size_t)(b - 864) * 8192; }
#pragma unroll
    for (int it = 0; it < 4; ++it)
        cvt8(src, dst, base + (size_t)it * 2048 + threadIdx.x * 8);
}

// QKV projections only (sg convert moved under flash): 768 blocks = 3/CU.
__global__ __launch_bounds__(256) void proj_qkv(
    const bf16_t* __restrict__ qB, const bf16_t* __restrict__ wqB, const float* __restrict__ bq,
    const bf16_t* __restrict__ kB, const bf16_t* __restrict__ wkB, const float* __restrict__ bk,
    const bf16_t* __restrict__ wvB, const bf16_t* __restrict__ vB, const float* __restrict__ bv,
    bf16_t* __restrict__ q, bf16_t* __restrict__ k, bf16_t* __restrict__ vt)
{
    const int b = blockIdx.x;
    const bf16_t *A, *B;
    const float *bc = nullptr, *br = nullptr;
    bf16_t* C;
    int ldc = 512, m0, n0;
    if (b < 512) {
        int i = b & 255, x = i & 7, t = i >> 3;
        n0 = (t & 7) * 64;
        m0 = ((t >> 3) * 8 + x) * 128;
        if (b < 256) { A = qB; B = wqB; bc = bq; C = q; }
        else         { A = kB; B = wkB; bc = bk; C = k; }
    } else {
        int i = b - 512;
        n0 = (i & 63) * 64;
        m0 = (i >> 6) * 128;
        A = wvB; B = vB; br = bv; C = vt; ldc = 4096;
    }
    gemm_body<bf16_t>(A, 512, B, 512, bc, br, C, ldc, 512, m0, n0);
}

// sgconv: TM=128/TN=64 body, 4-way K-split -> grid 1024 = 4 blocks/CU.
__global__ __launch_bounds__(256) void sgconv_gemm(
    const bf16_t* __restrict__ sgb, const bf16_t* __restrict__ aot,
    float* __restrict__ part)
{
    const int i = blockIdx.x & 255;          // 32 m-blocks x 8 n-blocks
    const int kb = blockIdx.x >> 8;          // 4 K-chunks
    const int ms = i & 31, ns = i >> 5;      // same-ms group lands on one XCD (32 % 8 == 0)
    const int m0 = ms * 128, n0 = ns * 64;
    const int kbase = kb * 1024;
    gemm_body<float>(sgb + kbase, 4096, aot + kbase, 4096, nullptr, nullptr,
                     part + (size_t)kb * (4096 * 512), 512, 1024, m0, n0);
}

// sum 4 fp32 partials -> bf16 o2 (one pass, coalesced)
__global__ __launch_bounds__(256) void part_reduce(
    const float* __restrict__ p, bf16_t* __restrict__ o2)
{
    const size_t S = (size_t)4096 * 512;
    const size_t idx = ((size_t)blockIdx.x * 256 + threadIdx.x) * 8;
    ushort8v u;
#pragma unroll
    for (int half = 0; half < 2; ++half) {
        float4 s = *(const float4*)(p + idx + half * 4);
#pragma unroll
        for (int kb = 1; kb < 4; ++kb) {
            float4 t = *(const float4*)(p + kb * S + idx + half * 4);
            s.x += t.x; s.y += t.y; s.z += t.z; s.w += t.w;
        }
        u[half * 4 + 0] = f2bf_rne(s.x);
        u[half * 4 + 1] = f2bf_rne(s.y);
        u[half * 4 + 2] = f2bf_rne(s.z);
        u[half * 4 + 3] = f2bf_rne(s.w);
    }
    *(ushort8v*)(o2 + idx) = u;
}

// out = o2 @ Wo^T + bo. TM=TN=64 (wave tile 32x32) -> grid 512 = 2 blocks/CU.
__global__ __launch_bounds__(256) void out_proj(
    const bf16_t* __restrict__ o2, const bf16_t* __restrict__ woB,
    const float* __restrict__ bo, float* __restrict__ out)
{
    const int i = blockIdx.x, x = i & 7, t = i >> 3;
    const int n0 = (t & 7) * 64;
    const int m0 = ((t >> 3) * 8 + x) * 64;

    __shared__ bf16_t As[64 * 68];
    __shared__ bf16_t Bs[64 * 68];

    const int tid = threadIdx.x;
    const int lane = tid & 63, wave = tid >> 6;
    const int wm = wave & 1, wn = wave >> 1;
    const int lo16 = lane & 15, quad = lane >> 4;
    const int sr = tid >> 2, sc = (tid & 3) * 8;

    floatx4 acc[2][2] = {};

    for (int k0 = 0; k0 < 512; k0 += 32) {
        bf16x8 a0 = *(const bf16x8*)(o2 + (size_t)(m0 + sr) * 512 + k0 + sc);
        bf16x8 b0 = *(const bf16x8*)(woB + (size_t)(n0 + sr) * 512 + k0 + sc);
        __syncthreads();
        *(bf16x8*)(&As[sr * 68 + sc]) = a0;
        *(bf16x8*)(&Bs[sr * 68 + sc]) = b0;
        __syncthreads();

        bf16x8 af[2], bfv[2];
#pragma unroll
        for (int mt = 0; mt < 2; ++mt)
            af[mt] = *(const bf16x8*)(&As[(wm * 32 + mt * 16 + lo16) * 68 + quad * 8]);
#pragma unroll
        for (int nt = 0; nt < 2; ++nt)
            bfv[nt] = *(const bf16x8*)(&Bs[(wn * 32 + nt * 16 + lo16) * 68 + quad * 8]);
#pragma unroll
        for (int mt = 0; mt < 2; ++mt)
#pragma unroll
            for (int nt = 0; nt < 2; ++nt)
                acc[mt][nt] = __builtin_amdgcn_mfma_f32_16x16x32_bf16(
                    af[mt], bfv[nt], acc[mt][nt], 0, 0, 0);
    }

#pragma unroll
    for (int nt = 0; nt < 2; ++nt) {
        const int gn = n0 + wn * 32 + nt * 16 + lo16;
        const float bc = bo[gn];
#pragma unroll
        for (int mt = 0; mt < 2; ++mt)
#pragma unroll
            for (int r = 0; r < 4; ++r) {
                const int gm = m0 + wm * 32 + mt * 16 + quad * 4 + r;
                out[(size_t)gm * 512 + gn] = acc[mt][nt][r] + bc;
            }
    }
}

// ---------------------------------------------------------------------------
// Flash attention (r6 body, best measured) + sg-convert blocks appended:
// blocks 0-1023 flash, 1024-3071 sg fp32->bf16 (HBM work hidden under flash).
// ---------------------------------------------------------------------------
__global__ __launch_bounds__(256, 4) void flash_attn(
    const bf16_t* __restrict__ q, const bf16_t* __restrict__ kk,
    const bf16_t* __restrict__ vt, float* __restrict__ op,
    float* __restrict__ lp, float scale,
    const float* __restrict__ sg, bf16_t* __restrict__ sgb)
{
    if (blockIdx.x >= 1024) {   // sg convert: 8192 elems/block, 2048 blocks
        const size_t base = (size_t)(blockIdx.x - 1024) * 8192;
#pragma unroll
        for (int it = 0; it < 4; ++it)
            cvt8(sg, sgb, base + (size_t)it * 2048 + threadIdx.x * 8);
        return;
    }

    const int N = 4096, D = 512;
    const int h   = blockIdx.x & 7;
    const int qb  = (blockIdx.x >> 3) & 31;
    const int qtr = blockIdx.x >> 8;
    const int t0  = qtr * 1024;

    const int tid = threadIdx.x;
    const int w = tid >> 6, lane = tid & 63;
    const int lo16 = lane & 15, quad = lane >> 4;

    __shared__ bf16_t Ks[64 * 72];
    __shared__ bf16_t Vs[64 * 72];
    __shared__ bf16_t Ps[4][32 * 72];

    const bf16_t* qp = q + (size_t)(qb * 128 + w * 32 + lo16) * D + h * 64 + quad * 8;
    bf16x8 qf[2][2];
    qf[0][0] = *(const bf16x8*)qp;
    qf[0][1] = *(const bf16x8*)(qp + 32);
    qf[1][0] = *(const bf16x8*)(qp + 16 * D);
    qf[1][1] = *(const bf16x8*)(qp + 16 * D + 32);

    const int srow = tid >> 2, sc = (tid & 3) * 16;
    const bf16_t* ksrc = kk + (size_t)(t0 + srow) * D + h * 64 + sc;
    const bf16_t* vsrc = vt + (size_t)(h * 64 + srow) * N + t0 + sc;
    bf16_t* kdst = &Ks[srow * 72 + sc];
    bf16_t* vdst = &Vs[srow * 72 + sc];

    floatx4 o[4][2] = {};
    float l[2] = {0.f, 0.f};

    bf16x8 kr0 = *(const bf16x8*)ksrc;
    bf16x8 kr1 = *(const bf16x8*)(ksrc + 8);
    bf16x8 vr0 = *(const bf16x8*)vsrc;
    bf16x8 vr1 = *(const bf16x8*)(vsrc + 8);

    for (int it = 0; it < 16; ++it) {
        __syncthreads();
        *(bf16x8*)kdst = kr0;  *(bf16x8*)(kdst + 8) = kr1;
        *(bf16x8*)vdst = vr0;  *(bf16x8*)(vdst + 8) = vr1;
        __syncthreads();
        if (it < 15) {
            const bf16_t* kn = ksrc + (size_t)(it + 1) * 64 * D;
            const bf16_t* vn = vsrc + (it + 1) * 64;
            kr0 = *(const bf16x8*)kn;  kr1 = *(const bf16x8*)(kn + 8);
            vr0 = *(const bf16x8*)vn;  vr1 = *(const bf16x8*)(vn + 8);
        }

        // S^T = K·Q^T : D[m=tok][n=q]
        floatx4 s[4][2];
#pragma unroll
        for (int tt = 0; tt < 4; ++tt) {
            bf16x8 kf0 = *(const bf16x8*)(&Ks[(tt * 16 + lo16) * 72 + quad * 8]);
            bf16x8 kf1 = *(const bf16x8*)(&Ks[(tt * 16 + lo16) * 72 + 32 + quad * 8]);
#pragma unroll
            for (int qt = 0; qt < 2; ++qt) {
                floatx4 a = {};
                a = __builtin_amdgcn_mfma_f32_16x16x32_bf16(kf0, qf[qt][0], a, 0, 0, 0);
                a = __builtin_amdgcn_mfma_f32_16x16x32_bf16(kf1, qf[qt][1], a, 0, 0, 0);
                s[tt][qt] = a;
            }
        }
        // exp + per-lane partial row sums + packed b64 P writes
#pragma unroll
        for (int tt = 0; tt < 4; ++tt)
#pragma unroll
            for (int qt = 0; qt < 2; ++qt) {
                float e0 = __expf(s[tt][qt][0] * scale);
                float e1 = __expf(s[tt][qt][1] * scale);
                float e2 = __expf(s[tt][qt][2] * scale);
                float e3 = __expf(s[tt][qt][3] * scale);
                l[qt] += (e0 + e1) + (e2 + e3);
                uint2 pk;
                pk.x = (unsigned)f2bf_rne(e0) | ((unsigned)f2bf_rne(e1) << 16);
                pk.y = (unsigned)f2bf_rne(e2) | ((unsigned)f2bf_rne(e3) << 16);
                *(uint2*)(&Ps[w][(qt * 16 + lo16) * 72 + tt * 16 + quad * 4]) = pk;
            }
        // PV: o[dim][q] += V·P^T
#pragma unroll
        for (int ks = 0; ks < 2; ++ks) {
            bf16x8 pf0 = *(const bf16x8*)(&Ps[w][lo16 * 72 + ks * 32 + quad * 8]);
            bf16x8 pf1 = *(const bf16x8*)(&Ps[w][(16 + lo16) * 72 + ks * 32 + quad * 8]);
#pragma unroll
            for (int t = 0; t < 4; ++t) {
                bf16x8 vf = *(const bf16x8*)(&Vs[(t * 16 + lo16) * 72 + ks * 32 + quad * 8]);
                o[t][0] = __builtin_amdgcn_mfma_f32_16x16x32_bf16(vf, pf0, o[t][0], 0, 0, 0);
                o[t][1] = __builtin_amdgcn_mfma_f32_16x16x32_bf16(vf, pf1, o[t][1], 0, 0, 0);
            }
        }
    }

#pragma unroll
    for (int qt = 0; qt < 2; ++qt) {
        l[qt] += __shfl_xor(l[qt], 16);
        l[qt] += __shfl_xor(l[qt], 32);
    }

    const int g = blockIdx.x & 255;
    float* opw = op + ((size_t)qtr * 256 + g) * 8192;
#pragma unroll
    for (int t = 0; t < 4; ++t)
#pragma unroll
        for (int pt = 0; pt < 2; ++pt)
#pragma unroll
            for (int r = 0; r < 4; ++r)
                opw[(t * 16 + quad * 4 + r) * 128 + w * 32 + pt * 16 + lo16] = o[t][pt][r];

    if (quad == 0) {
        float* lpw = lp + ((size_t)qtr * 256 + g) * 128;
        lpw[w * 32 + lo16] = l[0];
        lpw[w * 32 + 16 + lo16] = l[1];
    }
}

__global__ __launch_bounds__(256) void attn_combine(
    const float* __restrict__ op, const float* __restrict__ lp, bf16_t* __restrict__ aot)
{
    const int g = blockIdx.x;
    const int h = g & 7, qb = g >> 3;
    const int tid = threadIdx.x;
    __shared__ float ls[128];
    if (tid < 128) {
        float s = 0.f;
#pragma unroll
        for (int qtr = 0; qtr < 4; ++qtr)
            s += lp[((size_t)qtr * 256 + g) * 128 + tid];
        ls[tid] = 1.0f / s;
    }
    __syncthreads();
    const float* b0 = op + (size_t)g * 8192;
    const size_t QS = (size_t)256 * 8192;
#pragma unroll 4
    for (int i = 0; i < 32; ++i) {
        int idx = i * 256 + tid;
        float v = b0[idx] + b0[QS + idx] + b0[2 * QS + idx] + b0[3 * QS + idx];
        int dim = idx >> 7, qc = idx & 127;
        aot[(size_t)(h * 64 + dim) * 4096 + qb * 128 + qc] = f2bf(v * ls[qc]);
    }
}

extern "C" void kernel_launch(void* const* d_in, const int* in_sizes, int n_in,
                              void* d_out, int out_size, void* d_ws, size_t ws_size,
                              hipStream_t stream)
{
    const int N = 4096, D = 512;
    const float* query = (const float*)d_in[0];
    const float* key_t = (const float*)d_in[1];
    const float* value = (const float*)d_in[2];
    const float* Wq = (const float*)d_in[3];
    const float* bq = (const float*)d_in[4];
    const float* Wk = (const float*)d_in[5];
    const float* bk = (const float*)d_in[6];
    const float* Wv = (const float*)d_in[7];
    const float* bv = (const float*)d_in[8];
    const float* Wo = (const float*)d_in[9];
    const float* bo = (const float*)d_in[10];
    const float* sg = (const float*)d_in[11];
    float* out = (float*)d_out;

    const size_t ND = (size_t)N * D;
    const size_t DD = (size_t)D * D;

    char* base = (char*)d_ws;
    bf16_t* q    = (bf16_t*)base;
    bf16_t* kk   = q   + ND;
    bf16_t* vt   = kk  + ND;
    bf16_t* aot  = vt  + ND;
    bf16_t* sgb  = aot + ND;
    char* regA   = (char*)(sgb + (size_t)N * N);
    // region A, phase 1: prep inputs
    bf16_t* qB   = (bf16_t*)regA;
    bf16_t* kB   = qB + ND;
    bf16_t* vB   = kB + ND;
    bf16_t* wqB  = vB + ND;
    bf16_t* wkB  = wqB + DD;
    bf16_t* wvB  = wkB + DD;
    // region A, phase 2: flash partials op; phase 3: sgconv partials p
    float* op    = (float*)regA;
    float* p     = (float*)regA;
    char* tail   = regA + (size_t)4 * 256 * 8192 * 4;
    float*  lp   = (float*)tail;
    bf16_t* woB  = (bf16_t*)(lp + (size_t)4 * 256 * 128);
    bf16_t* o2   = woB + DD;

    const dim3 blk(256);

    prep<<<896, blk, 0, stream>>>(query, key_t, value, Wq, Wk, Wv, Wo,
                                  qB, kB, vB, wqB, wkB, wvB, woB);

    proj_qkv<<<768, blk, 0, stream>>>(qB, wqB, bq, kB, wkB, bk,
                                      wvB, vB, bv, q, kk, vt);

    const float scale = 1.0f / sqrtf((float)D);
    flash_attn<<<3072, blk, 0, stream>>>(q, kk, vt, op, lp, scale, sg, sgb);
    attn_combine<<<256, blk, 0, stream>>>(op, lp, aot);

    sgconv_gemm<<<1024, blk, 0, stream>>>(sgb, aot, p);
    part_reduce<<<1024, blk, 0, stream>>>(p, o2);
    out_proj<<<512, blk, 0, stream>>>(o2, woB, bo, out);

    (void)in_sizes; (void)n_in; (void)out_size; (void)ws_size;
}